// Round 9
// baseline (80.004 us; speedup 1.0000x reference)
//
#include <hip/hip_runtime.h>
#include <hip/hip_bf16.h>

// LocalCausalAttention: B=2, N=2048, D=1024, H=16, DH=64, WINDOW=64
// out = ( softmax(mask(QK^T*0.125)) V ) Wout^T + bout,  QKV = x Wqkv^T + bqkv
//
// R9: R6's best-measured QKV structure (128^2 tile, BK=32, 2-buffer counted-vmcnt,
//     3 blocks/CU) + VALU-address-calc removal (R6's 40.7% VALUBusy co-bottleneck):
//   - staging source pointers computed ONCE, incremented +64B/step (4 ptr adds/step)
//   - LDS read/write offsets hoisted to loop-invariant regs; per-step only
//     po = (t&1)<<14 parity add
//   - per step: {8 ds_read_b128 ; 16 MFMA ; lgkmcnt(0) ; bar ;
//                4 gloads (ptr+=) ; vmcnt(4) ; bar}   (R6-verified ledger)
//   - V transposed via LDS in the epilogue (R8-verified), transpose_v stays deleted.
//   outproj/cvt3/attn identical to R8 (attribution).

typedef __attribute__((ext_vector_type(8))) __bf16 bf16x8;
typedef __attribute__((ext_vector_type(4))) float f32x4;

#define GLOAD16(g, l)                                              \
  __builtin_amdgcn_global_load_lds(                                \
      (const __attribute__((address_space(1))) void*)(g),          \
      (__attribute__((address_space(3))) void*)(l), 16, 0, 0)

#define MFMA16(a, b, c) __builtin_amdgcn_mfma_f32_16x16x32_bf16((a), (b), (c), 0, 0, 0)

// ---------------- fused fp32 -> bf16 convert (x, Wqkv, Wout) ----------------
__global__ __launch_bounds__(256) void cvt3(const float* __restrict__ x,
                                            const float* __restrict__ wqkv,
                                            const float* __restrict__ wout,
                                            __bf16* __restrict__ xb,
                                            __bf16* __restrict__ wqkvb,
                                            __bf16* __restrict__ woutb) {
  const int blk = blockIdx.x;
  const float* src;
  __bf16* dst;
  int i;
  if (blk < 2048) {            // x: 4194304 elems
    src = x; dst = xb; i = (blk * 256 + (int)threadIdx.x) * 8;
  } else if (blk < 3584) {     // Wqkv: 3145728 elems
    src = wqkv; dst = wqkvb; i = ((blk - 2048) * 256 + (int)threadIdx.x) * 8;
  } else {                     // Wout: 1048576 elems
    src = wout; dst = woutb; i = ((blk - 3584) * 256 + (int)threadIdx.x) * 8;
  }
  f32x4 a = *(const f32x4*)(src + i);
  f32x4 b = *(const f32x4*)(src + i + 4);
  bf16x8 o;
  o[0] = (__bf16)a[0]; o[1] = (__bf16)a[1]; o[2] = (__bf16)a[2]; o[3] = (__bf16)a[3];
  o[4] = (__bf16)b[0]; o[5] = (__bf16)b[1]; o[6] = (__bf16)b[2]; o[7] = (__bf16)b[3];
  *(bf16x8*)(dst + i) = o;
}

// ---------------- 128^2 BK=32 counted-vmcnt QKV GEMM, hoisted addressing ----------------
// C[m,n] = sum_k A[m,k]*Wqkv[n,k] + bqkv[n]; M=4096,N=3072,K=1024 fixed.
// 4 waves (2x2), per-wave 64x64. LDS: 2x16KB bufs [A 8K|B 8K] + V-transpose tail region.
// Paired-row LDS layout (R6-verified, 0 conflicts): logical row r of 128B-line L=r>>1,
// slot u=((r&1)<<2)|g, stored at L*128 + ((u^(L&7))<<4).
__global__ __launch_bounds__(256) void gemm_qkv(
    const __bf16* __restrict__ A, const __bf16* __restrict__ Bw,
    const float* __restrict__ bias,
    __bf16* __restrict__ qo, __bf16* __restrict__ ko, __bf16* __restrict__ vt) {
  constexpr int K = 1024;
  __shared__ __align__(16) unsigned char Ls[36864];  // bufs [0,32768) + epilogue reuse
  const int tid = threadIdx.x;
  const int lane = tid & 63;
  const int wid = tid >> 6;
  const int wr = wid >> 1, wc = wid & 1;
  const int colL = lane & 15, g = lane >> 4;

  // T1: XCD chunking (768 blocks = 96/XCD, bijective), n fastest within chunk
  int s = (int)blockIdx.x;
  s = (s & 7) * 96 + (s >> 3);
  const int m0 = (s / 24) * 128, n0 = (s % 24) * 128;

  const __bf16* Ap = A + (size_t)m0 * K;
  const __bf16* Bp = Bw + (size_t)n0 * K;

  // staging chunk geometry (2 chunks per matrix per thread), hoisted once
  const int c0 = tid, c1 = tid + 256;
  auto srcoff = [&](int c) {  // element offset (row*K + pcol*8); k added separately
    int L = c >> 3, s6 = c & 7, u = s6 ^ (L & 7);
    int row = (L << 1) | (u >> 2), p = u & 3;
    return (size_t)row * K + (p << 3);
  };
  const size_t soA0 = srcoff(c0), soA1 = srcoff(c1);
  const int dA0 = c0 * 16, dA1 = c1 * 16;           // LDS dests (buf0 offsets)
  const int dB0 = 8192 + c0 * 16, dB1 = 8192 + c1 * 16;

  // incremental source pointers, start at tile 2 (k=64); +32 elems per step
  const __bf16* pA0 = Ap + soA0 + 64;
  const __bf16* pA1 = Ap + soA1 + 64;
  const __bf16* pB0 = Bp + soA0 + 64;
  const __bf16* pB1 = Bp + soA1 + 64;

  // ds_read per-lane offsets (buf0 absolute), loop-invariant
  int adrA[4], adrB[4];
#pragma unroll
  for (int mi = 0; mi < 4; ++mi) {
    const int r = (wr << 6) + (mi << 4) + colL;
    adrA[mi] = (r >> 1) * 128 + (((((r & 1) << 2) | g) ^ ((r >> 1) & 7)) << 4);
    const int rn = (wc << 6) + (mi << 4) + colL;
    adrB[mi] = 8192 + (rn >> 1) * 128 + (((((rn & 1) << 2) | g) ^ ((rn >> 1) & 7)) << 4);
  }

  f32x4 acc[4][4] = {};

  // prologue: tile0 -> buf0, tile1 -> buf1
  GLOAD16(Ap + soA0, Ls + dA0);
  GLOAD16(Ap + soA1, Ls + dA1);
  GLOAD16(Bp + soA0, Ls + dB0);
  GLOAD16(Bp + soA1, Ls + dB1);
  GLOAD16(Ap + soA0 + 32, Ls + 16384 + dA0);
  GLOAD16(Ap + soA1 + 32, Ls + 16384 + dA1);
  GLOAD16(Bp + soA0 + 32, Ls + 16384 + dB0);
  GLOAD16(Bp + soA1 + 32, Ls + 16384 + dB1);
  asm volatile("s_waitcnt vmcnt(4)" ::: "memory");  // tile0 landed; tile1 in flight
  __builtin_amdgcn_s_barrier();

  for (int t = 0; t < 32; ++t) {
    const int po = (t & 1) << 14;
    const unsigned char* base = Ls + po;
    bf16x8 af[4], bf[4];
#pragma unroll
    for (int mi = 0; mi < 4; ++mi) af[mi] = *(const bf16x8*)(base + adrA[mi]);
#pragma unroll
    for (int ni = 0; ni < 4; ++ni) bf[ni] = *(const bf16x8*)(base + adrB[ni]);
#pragma unroll
    for (int mi = 0; mi < 4; ++mi)
#pragma unroll
      for (int ni = 0; ni < 4; ++ni)
        acc[mi][ni] = MFMA16(af[mi], bf[ni], acc[mi][ni]);
    // all this wave's ds_reads done before anyone may DMA-overwrite buf[cur]
    asm volatile("s_waitcnt lgkmcnt(0)" ::: "memory");
    __builtin_amdgcn_s_barrier();
    if (t < 30) {
      unsigned char* d = Ls + po;  // stage tile t+2 into just-retired buffer
      GLOAD16(pA0, d + dA0);
      GLOAD16(pA1, d + dA1);
      GLOAD16(pB0, d + dB0);
      GLOAD16(pB1, d + dB1);
      pA0 += 32; pA1 += 32; pB0 += 32; pB1 += 32;
      // in flight: tile t+1 (4) + t+2 (4); retire oldest 4 -> t+1 validated
      asm volatile("s_waitcnt vmcnt(4)" ::: "memory");
    } else {
      asm volatile("s_waitcnt vmcnt(0)" ::: "memory");  // tail
    }
    __builtin_amdgcn_s_barrier();
  }

  // epilogue: C/D layout col=lane&15, row=(lane>>4)*4+reg (m89-verified)
  const int Cn0 = n0 + (wc << 6);              // wave's 64-col half: sx/h const
  const int sx = Cn0 >> 10, h = (Cn0 >> 6) & 15;
  float bv[4];
#pragma unroll
  for (int ni = 0; ni < 4; ++ni) bv[ni] = bias[Cn0 + (ni << 4) + colL];
  const int b = m0 >> 11;
  if (sx == 2) {
    // ---- V: transpose via LDS, write coalesced rows of Vt[bh][d][2048] (R8-verified) ----
    unsigned char* wreg = Ls + wid * 9216;     // per-wave [64][72] bf16 (pad -> ~2-way)
#pragma unroll
    for (int mi = 0; mi < 4; ++mi)
#pragma unroll
      for (int ni = 0; ni < 4; ++ni)
#pragma unroll
        for (int jp = 0; jp < 2; ++jp) {
          const int tt = (mi << 4) + (g << 2) + (jp << 1);
          const int d = (ni << 4) + colL;
          unsigned short u0 = __builtin_bit_cast(
              unsigned short, (__bf16)(acc[mi][ni][jp * 2] + bv[ni]));
          unsigned short u1 = __builtin_bit_cast(
              unsigned short, (__bf16)(acc[mi][ni][jp * 2 + 1] + bv[ni]));
          *(unsigned int*)(wreg + ((d * 72 + tt) << 1)) =
              (unsigned int)u0 | ((unsigned int)u1 << 16);
        }
    asm volatile("s_waitcnt lgkmcnt(0)" ::: "memory");
    const size_t vbase = (size_t)(b * 16 + h) * 64 * 2048;
    const int tg0 = (m0 & 2047) + (wr << 6);
#pragma unroll
    for (int i = 0; i < 32; ++i) {
      const int d = (i << 1) + (lane >> 5);
      const int toff = (lane & 31) << 1;
      unsigned int v = *(unsigned int*)(wreg + (d * 144 + ((lane & 31) << 2)));
      *(unsigned int*)((unsigned short*)vt + vbase + (size_t)d * 2048 + tg0 + toff) = v;
    }
  } else {
    __bf16* dst = (sx == 0) ? qo : ko;
    const float mul = (sx == 0) ? 0.125f : 1.0f;  // fold SCALE into Q (exact pow2)
#pragma unroll
    for (int mi = 0; mi < 4; ++mi) {
#pragma unroll
      for (int j = 0; j < 4; ++j) {
        const int Rm = m0 + (wr << 6) + (mi << 4) + (g << 2) + j;
        const int tt = Rm & 2047;
        __bf16* rowp = dst + (((size_t)b * 16 + h) * 2048 + tt) * 64;
#pragma unroll
        for (int ni = 0; ni < 4; ++ni)  // 4 x 32B bursts -> full 128B line
          rowp[(ni << 4) + colL] = (__bf16)((acc[mi][ni][j] + bv[ni]) * mul);
      }
    }
  }
}

// ---------------- 64x128 BK=64 counted-vmcnt dbuf GEMM (out-proj, R8-verified) ----------------
__global__ __launch_bounds__(128) void gemm_out(
    const __bf16* __restrict__ A, const __bf16* __restrict__ Bw,
    const float* __restrict__ bias, int N,
    float* __restrict__ outF, int nbn, int chunk) {
  constexpr int K = 1024;
  constexpr int ASZ = 8192;          // A half: 64 rows x 128B
  constexpr int BUF = ASZ + 16384;   // + B half: 128 rows x 128B
  __shared__ __align__(16) unsigned char Ls[2 * BUF];
  const int tid = threadIdx.x;
  const int lane = tid & 63;
  const int wc = tid >> 6;
  const int colL = lane & 15, g = lane >> 4;

  int s = (int)blockIdx.x;
  s = (s & 7) * chunk + (s >> 3);
  const int m0 = (s / nbn) * 64, n0 = (s % nbn) * 128;

  const __bf16* Ap = A + (size_t)m0 * K;
  const __bf16* Bp = Bw + (size_t)n0 * K;

  auto stageA = [&](unsigned char* lds, int k0) {
#pragma unroll
    for (int it = 0; it < 4; ++it) {
      int c = tid + it * 128;
      int row = c >> 3, p = c & 7, q = p ^ (row & 7);
      GLOAD16(Ap + (size_t)row * K + k0 + (q << 3), lds + c * 16);
    }
  };
  auto stageB = [&](unsigned char* lds, int k0) {
#pragma unroll
    for (int it = 0; it < 8; ++it) {
      int c = tid + it * 128;
      int row = c >> 3, p = c & 7, q = p ^ (row & 7);
      GLOAD16(Bp + (size_t)row * K + k0 + (q << 3), lds + c * 16);
    }
  };

  f32x4 acc[4][4] = {};

  stageA(Ls, 0);
  stageB(Ls + ASZ, 0);
  stageA(Ls + BUF, 64);
  stageB(Ls + BUF + ASZ, 64);
  asm volatile("s_waitcnt vmcnt(12)" ::: "memory");
  __builtin_amdgcn_s_barrier();

  constexpr int nT = 16;
  for (int t = 0; t < nT; ++t) {
    const unsigned char* Ab = Ls + (t & 1) * BUF;
    const unsigned char* Bb = Ab + ASZ;
    bf16x8 af[4][2], bf[4][2];
#pragma unroll
    for (int mi = 0; mi < 4; ++mi) {
      const int r = (mi << 4) + colL;
#pragma unroll
      for (int kk = 0; kk < 2; ++kk)
        af[mi][kk] = *(const bf16x8*)(Ab + r * 128 + ((((kk << 2) + g) ^ (r & 7)) << 4));
    }
#pragma unroll
    for (int ni = 0; ni < 4; ++ni) {
      const int r = (wc << 6) + (ni << 4) + colL;
#pragma unroll
      for (int kk = 0; kk < 2; ++kk)
        bf[ni][kk] = *(const bf16x8*)(Bb + r * 128 + ((((kk << 2) + g) ^ (r & 7)) << 4));
    }
#pragma unroll
    for (int mi = 0; mi < 4; ++mi)
#pragma unroll
      for (int ni = 0; ni < 4; ++ni) {
        acc[mi][ni] = MFMA16(af[mi][0], bf[ni][0], acc[mi][ni]);
        acc[mi][ni] = MFMA16(af[mi][1], bf[ni][1], acc[mi][ni]);
      }
    asm volatile("s_waitcnt lgkmcnt(0)" ::: "memory");
    __builtin_amdgcn_s_barrier();
    if (t < nT - 2) {
      const int kn = (t + 2) << 6;
      unsigned char* dst = Ls + (t & 1) * BUF;
      stageA(dst, kn);
      stageB(dst + ASZ, kn);
      asm volatile("s_waitcnt vmcnt(12)" ::: "memory");
    } else {
      asm volatile("s_waitcnt vmcnt(0)" ::: "memory");
    }
    __builtin_amdgcn_s_barrier();
  }

  float bv[4];
#pragma unroll
  for (int ni = 0; ni < 4; ++ni) bv[ni] = bias[n0 + (wc << 6) + (ni << 4) + colL];
#pragma unroll
  for (int mi = 0; mi < 4; ++mi) {
#pragma unroll
    for (int j = 0; j < 4; ++j) {
      const int Rm = m0 + (mi << 4) + (g << 2) + j;
      float* rowp = outF + (size_t)Rm * N + n0 + (wc << 6);
#pragma unroll
      for (int ni = 0; ni < 4; ++ni)
        rowp[(ni << 4) + colL] = acc[mi][ni][j] + bv[ni];
    }
  }
}

// ---------------- windowed attention ----------------
__global__ __launch_bounds__(256) void attn_win(const __bf16* __restrict__ Qb,
                                                const __bf16* __restrict__ Kb,
                                                const __bf16* __restrict__ Vt,
                                                __bf16* __restrict__ Ob) {
  const int bh = blockIdx.x >> 5;
  const int qb = blockIdx.x & 31;
  const int b = bh >> 4, h = bh & 15;
  __shared__ __align__(16) unsigned char Qs[64 * 128];
  __shared__ __align__(16) unsigned char Ks[128 * 128];
  __shared__ __align__(16) unsigned char Vs[64 * 256];
  __shared__ __align__(16) unsigned char Ps[4 * 16 * 272];
  const int tid = threadIdx.x;
  const int lane = tid & 63;
  const int w = tid >> 6;
  const int colL = lane & 15, g = lane >> 4;
  const __bf16* Qg = Qb + (size_t)bh * 2048 * 64;
  const __bf16* Kg = Kb + (size_t)bh * 2048 * 64;
  const __bf16* Vg = Vt + (size_t)bh * 64 * 2048;
  const int t0 = qb * 64 - 64;

#pragma unroll
  for (int it = 0; it < 2; ++it) {
    int c = tid + (it << 8);
    int r = c >> 3, p = c & 7, q = p ^ (r & 7);
    GLOAD16(Qg + (size_t)(qb * 64 + r) * 64 + (q << 3), Qs + c * 16);
  }
#pragma unroll
  for (int it = 0; it < 4; ++it) {
    int c = tid + (it << 8);
    int r = c >> 3, p = c & 7, q = p ^ (r & 7);
    int tok = t0 + r;
    tok = tok < 0 ? 0 : tok;
    GLOAD16(Kg + (size_t)tok * 64 + (q << 3), Ks + c * 16);
  }
#pragma unroll
  for (int it = 0; it < 4; ++it) {
    int c = tid + (it << 8);
    int r = c >> 4, p = c & 15, q = p ^ (r & 7);
    int tk = t0 + (q << 3);
    tk = tk < 0 ? 0 : tk;
    GLOAD16(Vg + (size_t)r * 2048 + tk, Vs + c * 16);
  }
  __syncthreads();

  f32x4 sc[8] = {};
  bf16x8 qf[2];
#pragma unroll
  for (int kk = 0; kk < 2; ++kk) {
    int r = (w << 4) + colL;
    int slot = (kk << 2) + g;
    qf[kk] = *(const bf16x8*)(Qs + r * 128 + ((slot ^ (r & 7)) << 4));
  }
#pragma unroll
  for (int ni = 0; ni < 8; ++ni) {
#pragma unroll
    for (int kk = 0; kk < 2; ++kk) {
      int r = (ni << 4) + colL;
      int slot = (kk << 2) + g;
      bf16x8 kf = *(const bf16x8*)(Ks + r * 128 + ((slot ^ (r & 7)) << 4));
      sc[ni] = MFMA16(qf[kk], kf, sc[ni]);
    }
  }

  float mx[4], sm[4];
#pragma unroll
  for (int j = 0; j < 4; ++j) mx[j] = -3.0e38f;
#pragma unroll
  for (int ni = 0; ni < 8; ++ni) {
#pragma unroll
    for (int j = 0; j < 4; ++j) {
      const int qi = (w << 4) + (g << 2) + j;
      const int ki = (ni << 4) + colL;
      const bool valid = (ki > qi) && (ki <= qi + 64) && (qb > 0 || ki >= 64);
      if (!valid) sc[ni][j] = -3.0e38f;
      mx[j] = fmaxf(mx[j], sc[ni][j]);
    }
  }
#pragma unroll
  for (int j = 0; j < 4; ++j) {
    mx[j] = fmaxf(mx[j], __shfl_xor(mx[j], 1));
    mx[j] = fmaxf(mx[j], __shfl_xor(mx[j], 2));
    mx[j] = fmaxf(mx[j], __shfl_xor(mx[j], 4));
    mx[j] = fmaxf(mx[j], __shfl_xor(mx[j], 8));
    sm[j] = 0.0f;
  }
  unsigned char* ps = Ps + w * (16 * 272);
#pragma unroll
  for (int ni = 0; ni < 8; ++ni) {
#pragma unroll
    for (int j = 0; j < 4; ++j) {
      float p = __expf(sc[ni][j] - mx[j]);
      sm[j] += p;
      *(__bf16*)(ps + ((g << 2) + j) * 272 + (((ni << 4) + colL) << 1)) = (__bf16)p;
    }
  }
#pragma unroll
  for (int j = 0; j < 4; ++j) {
    sm[j] += __shfl_xor(sm[j], 1);
    sm[j] += __shfl_xor(sm[j], 2);
    sm[j] += __shfl_xor(sm[j], 4);
    sm[j] += __shfl_xor(sm[j], 8);
  }
  __syncthreads();

  f32x4 o[4] = {};
#pragma unroll
  for (int step = 0; step < 4; ++step) {
    bf16x8 pf = *(const bf16x8*)(ps + colL * 272 + (step << 6) + (g << 4));
#pragma unroll
    for (int dt = 0; dt < 4; ++dt) {
      int r = (dt << 4) + colL;
      int slot = (step << 2) + g;
      bf16x8 vf = *(const bf16x8*)(Vs + r * 256 + ((slot ^ (r & 7)) << 4));
      o[dt] = MFMA16(pf, vf, o[dt]);
    }
  }

  float rinv[4];
#pragma unroll
  for (int j = 0; j < 4; ++j) rinv[j] = 1.0f / sm[j];
#pragma unroll
  for (int dt = 0; dt < 4; ++dt) {
#pragma unroll
    for (int j = 0; j < 4; ++j) {
      const int t = qb * 64 + (w << 4) + (g << 2) + j;
      Ob[((size_t)b * 2048 + t) * 1024 + h * 64 + (dt << 4) + colL] =
          (__bf16)(o[dt][j] * rinv[j]);
    }
  }
}

extern "C" void kernel_launch(void* const* d_in, const int* in_sizes, int n_in,
                              void* d_out, int out_size, void* d_ws, size_t ws_size,
                              hipStream_t stream) {
  const float* x = (const float*)d_in[0];     // [2,2048,1024]
  const float* Wqkv = (const float*)d_in[1];  // [3072,1024]
  const float* bqkv = (const float*)d_in[2];  // [3072]
  const float* Wout = (const float*)d_in[3];  // [1024,1024]
  const float* bout = (const float*)d_in[4];  // [1024]
  float* out = (float*)d_out;                 // [2,2048,1024] fp32

  __bf16* xb = (__bf16*)d_ws;             // 4194304
  __bf16* Wqkvb = xb + 4194304;           // 3145728
  __bf16* Woutb = Wqkvb + 3145728;        // 1048576
  __bf16* Qb = Woutb + 1048576;           // 4194304 each: [B,H,2048,64]
  __bf16* Kb = Qb + 4194304;
  __bf16* Vtb = Kb + 4194304;             // [B,H,64,2048] (written transposed by gemm)
  __bf16* AOb = Vtb + 4194304;            // attn out [B,2048,1024]

  cvt3<<<4096, 256, 0, stream>>>(x, Wqkv, Wout, xb, Wqkvb, Woutb);
  gemm_qkv<<<768, 256, 0, stream>>>(xb, Wqkvb, bqkv, Qb, Kb, Vtb);
  attn_win<<<1024, 256, 0, stream>>>(Qb, Kb, Vtb, AOb);
  gemm_out<<<512, 128, 0, stream>>>(AOb, Woutb, bout, 1024, out, 8, 64);
}

// Round 10
// 79.398 us; speedup vs baseline: 1.0076x; 1.0076x over previous
//
#include <hip/hip_runtime.h>
#include <hip/hip_bf16.h>

// LocalCausalAttention: B=2, N=2048, D=1024, H=16, DH=64, WINDOW=64
// out = ( softmax(mask(QK^T*0.125)) V ) Wout^T + bout,  QKV = x Wqkv^T + bqkv
//
// R10: scoreboard-driven composition.
//   QKV = R6's EXACT champion loop (128^2, BK=32, 2-buffer counted-vmcnt, stage2
//   recomputed addressing -- R9's hoisting reverted, it regressed 46.7->52)
//   + 2D per-XCD rectangle swizzle (8m x 12n per XCD: working set 2MB A + 3MB B
//     vs old 1MB+6MB -> B no longer thrashes the 4MB XCD L2; FETCH 54MB -> ~30MB)
//   + R8's V-LDS-transpose epilogue (transpose_v stays deleted).
//   out-proj/cvt3/attn = R8 (best-total round).

typedef __attribute__((ext_vector_type(8))) __bf16 bf16x8;
typedef __attribute__((ext_vector_type(4))) float f32x4;

#define GLOAD16(g, l)                                              \
  __builtin_amdgcn_global_load_lds(                                \
      (const __attribute__((address_space(1))) void*)(g),          \
      (__attribute__((address_space(3))) void*)(l), 16, 0, 0)

#define MFMA16(a, b, c) __builtin_amdgcn_mfma_f32_16x16x32_bf16((a), (b), (c), 0, 0, 0)

// ---------------- fused fp32 -> bf16 convert (x, Wqkv, Wout) ----------------
__global__ __launch_bounds__(256) void cvt3(const float* __restrict__ x,
                                            const float* __restrict__ wqkv,
                                            const float* __restrict__ wout,
                                            __bf16* __restrict__ xb,
                                            __bf16* __restrict__ wqkvb,
                                            __bf16* __restrict__ woutb) {
  const int blk = blockIdx.x;
  const float* src;
  __bf16* dst;
  int i;
  if (blk < 2048) {            // x: 4194304 elems
    src = x; dst = xb; i = (blk * 256 + (int)threadIdx.x) * 8;
  } else if (blk < 3584) {     // Wqkv: 3145728 elems
    src = wqkv; dst = wqkvb; i = ((blk - 2048) * 256 + (int)threadIdx.x) * 8;
  } else {                     // Wout: 1048576 elems
    src = wout; dst = woutb; i = ((blk - 3584) * 256 + (int)threadIdx.x) * 8;
  }
  f32x4 a = *(const f32x4*)(src + i);
  f32x4 b = *(const f32x4*)(src + i + 4);
  bf16x8 o;
  o[0] = (__bf16)a[0]; o[1] = (__bf16)a[1]; o[2] = (__bf16)a[2]; o[3] = (__bf16)a[3];
  o[4] = (__bf16)b[0]; o[5] = (__bf16)b[1]; o[6] = (__bf16)b[2]; o[7] = (__bf16)b[3];
  *(bf16x8*)(dst + i) = o;
}

// ---------------- 128^2 BK=32 counted-vmcnt QKV GEMM (R6 loop, 2D-XCD swizzle) ----
// C[m,n] = sum_k A[m,k]*Wqkv[n,k] + bqkv[n]; M=4096,N=3072,K=1024 fixed.
// 4 waves (2x2), per-wave 64x64. LDS: 2x16KB bufs + V-transpose epilogue reuse.
__global__ __launch_bounds__(256) void gemm_qkv(
    const __bf16* __restrict__ A, const __bf16* __restrict__ Bw,
    const float* __restrict__ bias,
    __bf16* __restrict__ qo, __bf16* __restrict__ ko, __bf16* __restrict__ vt) {
  constexpr int K = 1024;
  __shared__ __align__(16) unsigned char Ls[36864];  // bufs [0,32768) + epilogue region
  const int tid = threadIdx.x;
  const int lane = tid & 63;
  const int wid = tid >> 6;
  const int wr = wid >> 1, wc = wid & 1;
  const int colL = lane & 15, g = lane >> 4;

  // 2D per-XCD rectangle: xcd = blk&7 owns an 8m x 12n rectangle (bijective, 96 blocks)
  {
  }
  const int xcd = (int)blockIdx.x & 7;
  const int i = (int)blockIdx.x >> 3;          // [0,96)
  const int mR = (xcd >> 1) * 8 + i / 12;      // [0,32)
  const int nR = (xcd & 1) * 12 + i % 12;      // [0,24)
  const int m0 = mR * 128, n0 = nR * 128;

  const __bf16* Ap = A + (size_t)m0 * K;
  const __bf16* Bp = Bw + (size_t)n0 * K;

  // stage one matrix half-step (128 rows x 32 cols = 8KB), paired-row layout:
  // linear LDS dest c*16; line L=c>>3, s6=c&7; u=s6^(L&7) -> row=2L+(u>>2), p=u&3.
  auto stage2 = [&](const __bf16* src, unsigned char* lds, int k0) {
#pragma unroll
    for (int it = 0; it < 2; ++it) {
      int c = tid + (it << 8);       // 0..511
      int L = c >> 3, s6 = c & 7;
      int u = s6 ^ (L & 7);
      int row = (L << 1) | (u >> 2), p = u & 3;
      GLOAD16(src + (size_t)row * K + k0 + (p << 3), lds + c * 16);
    }
  };

  f32x4 acc[4][4] = {};

  // prologue: tiles 0,1 into bufs 0,1
  stage2(Ap, Ls, 0);
  stage2(Bp, Ls + 8192, 0);
  stage2(Ap, Ls + 16384, 32);
  stage2(Bp, Ls + 24576, 32);
  asm volatile("s_waitcnt vmcnt(4)" ::: "memory");  // tile0 landed; tile1 in flight
  __builtin_amdgcn_s_barrier();

  const int nT = K >> 5;  // 32 steps
  for (int t = 0; t < nT; ++t) {
    const unsigned char* Ab = Ls + (t & 1) * 16384;
    const unsigned char* Bb = Ab + 8192;
    bf16x8 af[4], bf[4];
#pragma unroll
    for (int mi = 0; mi < 4; ++mi) {
      const int r = (wr << 6) + (mi << 4) + colL;
      af[mi] = *(const bf16x8*)(Ab + (r >> 1) * 128 +
                                (((((r & 1) << 2) | g) ^ ((r >> 1) & 7)) << 4));
    }
#pragma unroll
    for (int ni = 0; ni < 4; ++ni) {
      const int r = (wc << 6) + (ni << 4) + colL;
      bf[ni] = *(const bf16x8*)(Bb + (r >> 1) * 128 +
                                (((((r & 1) << 2) | g) ^ ((r >> 1) & 7)) << 4));
    }
#pragma unroll
    for (int mi = 0; mi < 4; ++mi)
#pragma unroll
      for (int ni = 0; ni < 4; ++ni)
        acc[mi][ni] = MFMA16(af[mi], bf[ni], acc[mi][ni]);
    // all this wave's ds_reads executed before anyone may DMA-overwrite buf[cur]
    asm volatile("s_waitcnt lgkmcnt(0)" ::: "memory");
    __builtin_amdgcn_s_barrier();
    if (t < nT - 2) {
      const int kn = (t + 2) << 5;
      unsigned char* dst = Ls + (t & 1) * 16384;  // overwrite just-retired buffer
      stage2(Ap, dst, kn);
      stage2(Bp, dst + 8192, kn);
      // in flight: tile t+1 (4) + tile t+2 (4); retire oldest 4 -> t+1 validated
      asm volatile("s_waitcnt vmcnt(4)" ::: "memory");
    } else {
      asm volatile("s_waitcnt vmcnt(0)" ::: "memory");  // tail: drain last tile
    }
    __builtin_amdgcn_s_barrier();
  }

  // epilogue: C/D layout col=lane&15, row=(lane>>4)*4+reg (m89-verified)
  const int Cn0 = n0 + (wc << 6);              // wave's 64-col half: sx/h const
  const int sx = Cn0 >> 10, h = (Cn0 >> 6) & 15;
  float bv[4];
#pragma unroll
  for (int ni = 0; ni < 4; ++ni) bv[ni] = bias[Cn0 + (ni << 4) + colL];
  const int b = m0 >> 11;
  if (sx == 2) {
    // ---- V: transpose via LDS, write coalesced rows of Vt[bh][d][2048] (R8-verified) ----
    unsigned char* wreg = Ls + wid * 9216;     // per-wave [64][72] bf16 (pad -> ~2-way)
#pragma unroll
    for (int mi = 0; mi < 4; ++mi)
#pragma unroll
      for (int ni = 0; ni < 4; ++ni)
#pragma unroll
        for (int jp = 0; jp < 2; ++jp) {
          const int tt = (mi << 4) + (g << 2) + (jp << 1);
          const int d = (ni << 4) + colL;
          unsigned short u0 = __builtin_bit_cast(
              unsigned short, (__bf16)(acc[mi][ni][jp * 2] + bv[ni]));
          unsigned short u1 = __builtin_bit_cast(
              unsigned short, (__bf16)(acc[mi][ni][jp * 2 + 1] + bv[ni]));
          *(unsigned int*)(wreg + ((d * 72 + tt) << 1)) =
              (unsigned int)u0 | ((unsigned int)u1 << 16);
        }
    asm volatile("s_waitcnt lgkmcnt(0)" ::: "memory");
    const size_t vbase = (size_t)(b * 16 + h) * 64 * 2048;
    const int tg0 = (m0 & 2047) + (wr << 6);
#pragma unroll
    for (int i2 = 0; i2 < 32; ++i2) {
      const int d = (i2 << 1) + (lane >> 5);
      const int toff = (lane & 31) << 1;
      unsigned int v = *(unsigned int*)(wreg + (d * 144 + ((lane & 31) << 2)));
      *(unsigned int*)((unsigned short*)vt + vbase + (size_t)d * 2048 + tg0 + toff) = v;
    }
  } else {
    __bf16* dst = (sx == 0) ? qo : ko;
    const float mul = (sx == 0) ? 0.125f : 1.0f;  // fold SCALE into Q (exact pow2)
#pragma unroll
    for (int mi = 0; mi < 4; ++mi) {
#pragma unroll
      for (int j = 0; j < 4; ++j) {
        const int Rm = m0 + (wr << 6) + (mi << 4) + (g << 2) + j;
        const int tt = Rm & 2047;
        __bf16* rowp = dst + (((size_t)b * 16 + h) * 2048 + tt) * 64;
#pragma unroll
        for (int ni = 0; ni < 4; ++ni)  // 4 x 32B bursts -> full 128B line
          rowp[(ni << 4) + colL] = (__bf16)((acc[mi][ni][j] + bv[ni]) * mul);
      }
    }
  }
}

// ---------------- 64x128 BK=64 counted-vmcnt dbuf GEMM (out-proj, R8-verified) ----------------
__global__ __launch_bounds__(128) void gemm_out(
    const __bf16* __restrict__ A, const __bf16* __restrict__ Bw,
    const float* __restrict__ bias, int N,
    float* __restrict__ outF, int nbn, int chunk) {
  constexpr int K = 1024;
  constexpr int ASZ = 8192;          // A half: 64 rows x 128B
  constexpr int BUF = ASZ + 16384;   // + B half: 128 rows x 128B
  __shared__ __align__(16) unsigned char Ls[2 * BUF];
  const int tid = threadIdx.x;
  const int lane = tid & 63;
  const int wc = tid >> 6;
  const int colL = lane & 15, g = lane >> 4;

  int s = (int)blockIdx.x;
  s = (s & 7) * chunk + (s >> 3);
  const int m0 = (s / nbn) * 64, n0 = (s % nbn) * 128;

  const __bf16* Ap = A + (size_t)m0 * K;
  const __bf16* Bp = Bw + (size_t)n0 * K;

  auto stageA = [&](unsigned char* lds, int k0) {
#pragma unroll
    for (int it = 0; it < 4; ++it) {
      int c = tid + it * 128;
      int row = c >> 3, p = c & 7, q = p ^ (row & 7);
      GLOAD16(Ap + (size_t)row * K + k0 + (q << 3), lds + c * 16);
    }
  };
  auto stageB = [&](unsigned char* lds, int k0) {
#pragma unroll
    for (int it = 0; it < 8; ++it) {
      int c = tid + it * 128;
      int row = c >> 3, p = c & 7, q = p ^ (row & 7);
      GLOAD16(Bp + (size_t)row * K + k0 + (q << 3), lds + c * 16);
    }
  };

  f32x4 acc[4][4] = {};

  stageA(Ls, 0);
  stageB(Ls + ASZ, 0);
  stageA(Ls + BUF, 64);
  stageB(Ls + BUF + ASZ, 64);
  asm volatile("s_waitcnt vmcnt(12)" ::: "memory");
  __builtin_amdgcn_s_barrier();

  constexpr int nT = 16;
  for (int t = 0; t < nT; ++t) {
    const unsigned char* Ab = Ls + (t & 1) * BUF;
    const unsigned char* Bb = Ab + ASZ;
    bf16x8 af[4][2], bf[4][2];
#pragma unroll
    for (int mi = 0; mi < 4; ++mi) {
      const int r = (mi << 4) + colL;
#pragma unroll
      for (int kk = 0; kk < 2; ++kk)
        af[mi][kk] = *(const bf16x8*)(Ab + r * 128 + ((((kk << 2) + g) ^ (r & 7)) << 4));
    }
#pragma unroll
    for (int ni = 0; ni < 4; ++ni) {
      const int r = (wc << 6) + (ni << 4) + colL;
#pragma unroll
      for (int kk = 0; kk < 2; ++kk)
        bf[ni][kk] = *(const bf16x8*)(Bb + r * 128 + ((((kk << 2) + g) ^ (r & 7)) << 4));
    }
#pragma unroll
    for (int mi = 0; mi < 4; ++mi)
#pragma unroll
      for (int ni = 0; ni < 4; ++ni) {
        acc[mi][ni] = MFMA16(af[mi][0], bf[ni][0], acc[mi][ni]);
        acc[mi][ni] = MFMA16(af[mi][1], bf[ni][1], acc[mi][ni]);
      }
    asm volatile("s_waitcnt lgkmcnt(0)" ::: "memory");
    __builtin_amdgcn_s_barrier();
    if (t < nT - 2) {
      const int kn = (t + 2) << 6;
      unsigned char* dst = Ls + (t & 1) * BUF;
      stageA(dst, kn);
      stageB(dst + ASZ, kn);
      asm volatile("s_waitcnt vmcnt(12)" ::: "memory");
    } else {
      asm volatile("s_waitcnt vmcnt(0)" ::: "memory");
    }
    __builtin_amdgcn_s_barrier();
  }

  float bv[4];
#pragma unroll
  for (int ni = 0; ni < 4; ++ni) bv[ni] = bias[n0 + (wc << 6) + (ni << 4) + colL];
#pragma unroll
  for (int mi = 0; mi < 4; ++mi) {
#pragma unroll
    for (int j = 0; j < 4; ++j) {
      const int Rm = m0 + (mi << 4) + (g << 2) + j;
      float* rowp = outF + (size_t)Rm * N + n0 + (wc << 6);
#pragma unroll
      for (int ni = 0; ni < 4; ++ni)
        rowp[(ni << 4) + colL] = acc[mi][ni][j] + bv[ni];
    }
  }
}

// ---------------- windowed attention ----------------
__global__ __launch_bounds__(256) void attn_win(const __bf16* __restrict__ Qb,
                                                const __bf16* __restrict__ Kb,
                                                const __bf16* __restrict__ Vt,
                                                __bf16* __restrict__ Ob) {
  const int bh = blockIdx.x >> 5;
  const int qb = blockIdx.x & 31;
  const int b = bh >> 4, h = bh & 15;
  __shared__ __align__(16) unsigned char Qs[64 * 128];
  __shared__ __align__(16) unsigned char Ks[128 * 128];
  __shared__ __align__(16) unsigned char Vs[64 * 256];
  __shared__ __align__(16) unsigned char Ps[4 * 16 * 272];
  const int tid = threadIdx.x;
  const int lane = tid & 63;
  const int w = tid >> 6;
  const int colL = lane & 15, g = lane >> 4;
  const __bf16* Qg = Qb + (size_t)bh * 2048 * 64;
  const __bf16* Kg = Kb + (size_t)bh * 2048 * 64;
  const __bf16* Vg = Vt + (size_t)bh * 64 * 2048;
  const int t0 = qb * 64 - 64;

#pragma unroll
  for (int it = 0; it < 2; ++it) {
    int c = tid + (it << 8);
    int r = c >> 3, p = c & 7, q = p ^ (r & 7);
    GLOAD16(Qg + (size_t)(qb * 64 + r) * 64 + (q << 3), Qs + c * 16);
  }
#pragma unroll
  for (int it = 0; it < 4; ++it) {
    int c = tid + (it << 8);
    int r = c >> 3, p = c & 7, q = p ^ (r & 7);
    int tok = t0 + r;
    tok = tok < 0 ? 0 : tok;
    GLOAD16(Kg + (size_t)tok * 64 + (q << 3), Ks + c * 16);
  }
#pragma unroll
  for (int it = 0; it < 4; ++it) {
    int c = tid + (it << 8);
    int r = c >> 4, p = c & 15, q = p ^ (r & 7);
    int tk = t0 + (q << 3);
    tk = tk < 0 ? 0 : tk;
    GLOAD16(Vg + (size_t)r * 2048 + tk, Vs + c * 16);
  }
  __syncthreads();

  f32x4 sc[8] = {};
  bf16x8 qf[2];
#pragma unroll
  for (int kk = 0; kk < 2; ++kk) {
    int r = (w << 4) + colL;
    int slot = (kk << 2) + g;
    qf[kk] = *(const bf16x8*)(Qs + r * 128 + ((slot ^ (r & 7)) << 4));
  }
#pragma unroll
  for (int ni = 0; ni < 8; ++ni) {
#pragma unroll
    for (int kk = 0; kk < 2; ++kk) {
      int r = (ni << 4) + colL;
      int slot = (kk << 2) + g;
      bf16x8 kf = *(const bf16x8*)(Ks + r * 128 + ((slot ^ (r & 7)) << 4));
      sc[ni] = MFMA16(qf[kk], kf, sc[ni]);
    }
  }

  float mx[4], sm[4];
#pragma unroll
  for (int j = 0; j < 4; ++j) mx[j] = -3.0e38f;
#pragma unroll
  for (int ni = 0; ni < 8; ++ni) {
#pragma unroll
    for (int j = 0; j < 4; ++j) {
      const int qi = (w << 4) + (g << 2) + j;
      const int ki = (ni << 4) + colL;
      const bool valid = (ki > qi) && (ki <= qi + 64) && (qb > 0 || ki >= 64);
      if (!valid) sc[ni][j] = -3.0e38f;
      mx[j] = fmaxf(mx[j], sc[ni][j]);
    }
  }
#pragma unroll
  for (int j = 0; j < 4; ++j) {
    mx[j] = fmaxf(mx[j], __shfl_xor(mx[j], 1));
    mx[j] = fmaxf(mx[j], __shfl_xor(mx[j], 2));
    mx[j] = fmaxf(mx[j], __shfl_xor(mx[j], 4));
    mx[j] = fmaxf(mx[j], __shfl_xor(mx[j], 8));
    sm[j] = 0.0f;
  }
  unsigned char* ps = Ps + w * (16 * 272);
#pragma unroll
  for (int ni = 0; ni < 8; ++ni) {
#pragma unroll
    for (int j = 0; j < 4; ++j) {
      float p = __expf(sc[ni][j] - mx[j]);
      sm[j] += p;
      *(__bf16*)(ps + ((g << 2) + j) * 272 + (((ni << 4) + colL) << 1)) = (__bf16)p;
    }
  }
#pragma unroll
  for (int j = 0; j < 4; ++j) {
    sm[j] += __shfl_xor(sm[j], 1);
    sm[j] += __shfl_xor(sm[j], 2);
    sm[j] += __shfl_xor(sm[j], 4);
    sm[j] += __shfl_xor(sm[j], 8);
  }
  __syncthreads();

  f32x4 o[4] = {};
#pragma unroll
  for (int step = 0; step < 4; ++step) {
    bf16x8 pf = *(const bf16x8*)(ps + colL * 272 + (step << 6) + (g << 4));
#pragma unroll
    for (int dt = 0; dt < 4; ++dt) {
      int r = (dt << 4) + colL;
      int slot = (step << 2) + g;
      bf16x8 vf = *(const bf16x8*)(Vs + r * 256 + ((slot ^ (r & 7)) << 4));
      o[dt] = MFMA16(pf, vf, o[dt]);
    }
  }

  float rinv[4];
#pragma unroll
  for (int j = 0; j < 4; ++j) rinv[j] = 1.0f / sm[j];
#pragma unroll
  for (int dt = 0; dt < 4; ++dt) {
#pragma unroll
    for (int j = 0; j < 4; ++j) {
      const int t = qb * 64 + (w << 4) + (g << 2) + j;
      Ob[((size_t)b * 2048 + t) * 1024 + h * 64 + (dt << 4) + colL] =
          (__bf16)(o[dt][j] * rinv[j]);
    }
  }
}

extern "C" void kernel_launch(void* const* d_in, const int* in_sizes, int n_in,
                              void* d_out, int out_size, void* d_ws, size_t ws_size,
                              hipStream_t stream) {
  const float* x = (const float*)d_in[0];     // [2,2048,1024]
  const float* Wqkv = (const float*)d_in[1];  // [3072,1024]
  const float* bqkv = (const float*)d_in[2];  // [3072]
  const float* Wout = (const float*)d_in[3];  // [1024,1024]
  const float* bout = (const float*)d_in[4];  // [1024]
  float* out = (float*)d_out;                 // [2,2048,1024] fp32

  __bf16* xb = (__bf16*)d_ws;             // 4194304
  __bf16* Wqkvb = xb + 4194304;           // 3145728
  __bf16* Woutb = Wqkvb + 3145728;        // 1048576
  __bf16* Qb = Woutb + 1048576;           // 4194304 each: [B,H,2048,64]
  __bf16* Kb = Qb + 4194304;
  __bf16* Vtb = Kb + 4194304;             // [B,H,64,2048] (written transposed by gemm)
  __bf16* AOb = Vtb + 4194304;            // attn out [B,2048,1024]

  cvt3<<<4096, 256, 0, stream>>>(x, Wqkv, Wout, xb, Wqkvb, Woutb);
  gemm_qkv<<<768, 256, 0, stream>>>(xb, Wqkvb, bqkv, Qb, Kb, Vtb);
  attn_win<<<1024, 256, 0, stream>>>(Qb, Kb, Vtb, AOb);
  gemm_out<<<512, 128, 0, stream>>>(AOb, Woutb, bout, 1024, out, 8, 64);
}